// Round 11
// baseline (99.090 us; speedup 1.0000x reference)
//
#include <hip/hip_runtime.h>
#include <stdint.h>

// Radius-graph edge list, B=4, N=2048, cutoff 5.0.
// Output [2, B*P] int32: compacted valid edges (ascending flat index), -1 pad.
// Pipeline (2 kernels, no inter-block communication, no grid barrier):
//   pass1: count + stash ONLY (no 67 MB fill -> pure compute, fast).
//   pass2: self-service sweep of all 2048 counts (8 KB, L2-hot) gives BOTH
//          this block's offset AND the global total T. Valid edges occupy
//          within-row positions < T exactly; pad occupies >= T. Fill own
//          slice positions >= T with -1 IN BOTH ROWS (R10 bug: row 1 was
//          filled unconditionally and raced with row-1 edge writes of early
//          blocks); copy stash edges to [off, off+cnt). Write sets disjoint
//          across blocks by construction. (Recompute fallback if cnt > kCap.)

namespace {
constexpr int kB = 4;
constexpr int kN = 2048;
constexpr int kP = kN * (kN - 1) / 2;              // 2096128
constexpr long long kTotal = (long long)kB * kP;   // 8384512
constexpr int kBlock = 256;
constexpr int kItems = 16;
constexpr int kChunk = kBlock * kItems;            // 4096
constexpr int kNBlk = (int)(kTotal / kChunk);      // 2047 (exact, no tail)
constexpr float kCut2 = 25.0f;                     // 5.0^2
constexpr int kCap = 128;                          // stash slots per chunk
}  // namespace

// p in [0,P) -> (i,j), i<j, triu row-major. Closed-form sqrt guess + exact
// integer fixup. C(i) = i*(4095-i)/2. disc < 2^24 so float sqrt is tight.
__device__ __forceinline__ void decode_pair(int p, int& i, int& j) {
  float t = sqrtf((float)(16769025 - 8 * p));
  int ii = (int)((4095.0f - t) * 0.5f);
  ii = ii < 0 ? 0 : (ii > kN - 2 ? kN - 2 : ii);
  while (ii > 0 && (ii * (4095 - ii)) / 2 > p) --ii;
  while (ii < kN - 2 && ((ii + 1) * (4094 - ii)) / 2 <= p) ++ii;
  i = ii;
  j = ii + 1 + (p - (ii * (4095 - ii)) / 2);
}

__global__ __launch_bounds__(kBlock) void pass1_kernel(const float* __restrict__ x,
                                                       uint32_t* __restrict__ counts,
                                                       int2* __restrict__ stash) {
  const int t = threadIdx.x;
  const int wave = t >> 6, lane = t & 63;
  const int bid = blockIdx.x;
  const int base = bid * kChunk;
  if (bid == 0 && t == 0) counts[kNBlk] = 0;  // pad so pass2 can uint4-load

  // One sqrt-decode per thread per block, then incremental row-walk (+256/item).
  int b = base / kP;
  int p = base - b * kP + t;
  if (p >= kP) { p -= kP; ++b; }
  int i, j;
  decode_pair(p, i, j);
  int ib = b * kN;  // point-index base of batch b

  const float3* __restrict__ x3 = (const float3*)x;
  float3 pi = x3[ib + i];

  uint32_t hits = 0;  // bit k = item k is an edge
#pragma unroll
  for (int k = 0; k < kItems; ++k) {
    float3 pj = x3[ib + j];
    float dx = pi.x - pj.x, dy = pi.y - pj.y, dz = pi.z - pj.z;
    if (dx * dx + dy * dy + dz * dz <= kCut2) hits |= (1u << k);
    if (k < kItems - 1) {
      j += kBlock;
      if (j >= kN) {  // mostly wave-coherent
        do {
          int ex = j - kN;
          ++i;
          if (i >= kN - 1) { i = 0; ib += kN; }
          j = i + 1 + ex;
        } while (j >= kN);
        pi = x3[ib + i];
      }
    }
  }

  __shared__ uint32_t slot[kItems * 4];  // 64 (item,wave) counts
  if (t < 64) slot[t] = 0;
  __syncthreads();

  const bool waveany = (__ballot(hits != 0) != 0ULL);  // wave-uniform
  if (waveany) {
#pragma unroll
    for (int k = 0; k < kItems; ++k) {
      unsigned long long m = __ballot((hits >> k) & 1u);
      if (m != 0ULL && lane == 0) slot[k * 4 + wave] = (uint32_t)__popcll(m);
    }
  }
  __syncthreads();
  if (t < 64) {  // one-wave exclusive scan of 64 slots; write block total
    uint32_t v = slot[t];
    uint32_t run = v;
    for (int off = 1; off < 64; off <<= 1) {
      uint32_t u = __shfl_up(run, off, 64);
      if (t >= off) run += u;
    }
    slot[t] = run - v;
    if (t == 63) counts[bid] = run;
  }
  __syncthreads();
  if (waveany) {
#pragma unroll
    for (int k = 0; k < kItems; ++k) {
      bool f = (hits >> k) & 1u;
      unsigned long long m = __ballot(f);
      if (m != 0ULL && f) {  // rare: ~6 hits per block total
        int pf = base + k * kBlock + t;
        int hb = pf / kP;
        int hp = pf - hb * kP;
        int hi, hj;
        decode_pair(hp, hi, hj);
        uint32_t pos = slot[k * 4 + wave] +
                       (uint32_t)__popcll(m & ((1ULL << lane) - 1ULL));
        if (pos < (uint32_t)kCap)
          stash[(size_t)bid * kCap + pos] = make_int2(hb * kN + hi, hb * kN + hj);
      }
    }
  }
}

__global__ __launch_bounds__(kBlock) void pass2_kernel(const float* __restrict__ x,
                                                       const uint32_t* __restrict__ counts,
                                                       const int2* __restrict__ stash,
                                                       int* __restrict__ out) {
  const int bid = blockIdx.x;
  const int t = threadIdx.x;
  const int base = bid * kChunk;

  // Self-service sweep: this block's offset AND the global total T.
  const uint4* c4 = (const uint4*)counts;  // [2048] incl. zero pad
  uint32_t partOff = 0, partTot = 0;
#pragma unroll
  for (int q = 0; q < 2; ++q) {
    uint4 v = c4[t * 2 + q];
    int i0 = t * 8 + q * 4;
    partTot += v.x + v.y + v.z + v.w;
    partOff += (i0 + 0 < bid) ? v.x : 0u;
    partOff += (i0 + 1 < bid) ? v.y : 0u;
    partOff += (i0 + 2 < bid) ? v.z : 0u;
    partOff += (i0 + 3 < bid) ? v.w : 0u;
  }
  for (int o = 32; o > 0; o >>= 1) {
    partOff += __shfl_down(partOff, o, 64);
    partTot += __shfl_down(partTot, o, 64);
  }
  __shared__ uint32_t wOff[4], wTot[4];
  if ((t & 63) == 0) { wOff[t >> 6] = partOff; wTot[t >> 6] = partTot; }
  __syncthreads();
  if (t == 0) {
    wOff[0] = wOff[0] + wOff[1] + wOff[2] + wOff[3];
    wTot[0] = wTot[0] + wTot[1] + wTot[2] + wTot[3];
  }
  __syncthreads();
  const uint32_t off = wOff[0];
  const uint32_t T = wTot[0];
  const uint32_t cnt = counts[bid];

  // Fill own slice positions >= T with -1 — SAME guard for BOTH rows (the
  // within-row position base+idx decides pad vs edge territory; R10 raced
  // by filling row 1 unconditionally).
  {
    const int4 m1 = make_int4(-1, -1, -1, -1);
    int4* o0 = (int4*)out + (base >> 2);
    int4* o1 = (int4*)(out + kTotal) + (base >> 2);
    if ((uint32_t)base >= T) {  // whole slice is pad (true for all but ~3 blocks)
#pragma unroll
      for (int q = 0; q < 4; ++q) {
        o0[t + q * kBlock] = m1;
        o1[t + q * kBlock] = m1;
      }
    } else if ((uint32_t)(base + kChunk) <= T) {
      // whole slice is edge territory: nothing to fill in either row
    } else {
      // straddles T: per-int4, then per-element guard on both rows
      for (int q = 0; q < 4; ++q) {
        int e0 = base + (t + q * kBlock) * 4;
        if ((uint32_t)e0 >= T) {
          o0[t + q * kBlock] = m1;
          o1[t + q * kBlock] = m1;
        } else {
          for (int r = 0; r < 4; ++r) {
            if ((uint32_t)(e0 + r) >= T) {
              out[e0 + r] = -1;
              out[(size_t)kTotal + e0 + r] = -1;
            }
          }
        }
      }
    }
  }

  if (cnt == 0) return;
  if (cnt <= (uint32_t)kCap) {
    for (uint32_t e = t; e < cnt; e += kBlock) {
      int2 v = stash[(size_t)bid * kCap + e];
      out[off + e] = v.x;
      out[(size_t)kTotal + off + e] = v.y;
    }
    return;
  }
  // Overflow fallback (cnt > kCap): recompute this chunk's edges with
  // ballot ranks and write directly (all positions < T). Exact.
  const int wave = t >> 6, lane = t & 63;
  __shared__ uint32_t slot[kItems * 4];
  if (t < 64) slot[t] = 0;
  __syncthreads();
  uint32_t hits = 0;
#pragma unroll
  for (int k = 0; k < kItems; ++k) {
    int pf = base + k * kBlock + t;
    int hb = pf / kP;
    int hp = pf - hb * kP;
    int hi, hj;
    decode_pair(hp, hi, hj);
    const float* xb = x + (size_t)hb * kN * 3;
    float dx = xb[3 * hi] - xb[3 * hj];
    float dy = xb[3 * hi + 1] - xb[3 * hj + 1];
    float dz = xb[3 * hi + 2] - xb[3 * hj + 2];
    bool f = dx * dx + dy * dy + dz * dz <= kCut2;
    if (f) hits |= (1u << k);
    unsigned long long m = __ballot(f);
    if (m != 0ULL && lane == 0) slot[k * 4 + wave] = (uint32_t)__popcll(m);
  }
  __syncthreads();
  if (t < 64) {
    uint32_t v = slot[t];
    uint32_t run = v;
    for (int o = 1; o < 64; o <<= 1) {
      uint32_t u = __shfl_up(run, o, 64);
      if (t >= o) run += u;
    }
    slot[t] = run - v;
  }
  __syncthreads();
#pragma unroll
  for (int k = 0; k < kItems; ++k) {
    bool f = (hits >> k) & 1u;
    unsigned long long m = __ballot(f);
    if (m != 0ULL && f) {
      int pf = base + k * kBlock + t;
      int hb = pf / kP;
      int hp = pf - hb * kP;
      int hi, hj;
      decode_pair(hp, hi, hj);
      uint32_t pos = off + slot[k * 4 + wave] +
                     (uint32_t)__popcll(m & ((1ULL << lane) - 1ULL));
      out[pos] = hb * kN + hi;
      out[(size_t)kTotal + pos] = hb * kN + hj;
    }
  }
}

extern "C" void kernel_launch(void* const* d_in, const int* in_sizes, int n_in,
                              void* d_out, int out_size, void* d_ws, size_t ws_size,
                              hipStream_t stream) {
  const float* x = (const float*)d_in[0];
  int* out = (int*)d_out;
  uint32_t* counts = (uint32_t*)d_ws;                 // [2048] (1 pad)
  int2* stash = (int2*)(counts + 2048);               // [2047 * kCap] ~2.1 MB

  hipLaunchKernelGGL(pass1_kernel, dim3(kNBlk), dim3(kBlock), 0, stream, x, counts,
                     stash);
  hipLaunchKernelGGL(pass2_kernel, dim3(kNBlk), dim3(kBlock), 0, stream, x, counts,
                     stash, out);
}

// Round 12
// 95.754 us; speedup vs baseline: 1.0348x; 1.0348x over previous
//
#include <hip/hip_runtime.h>
#include <stdint.h>

// Radius-graph edge list, B=4, N=2048, cutoff 5.0.
// Output [2, B*P] int32: compacted valid edges (ascending flat index), -1 pad.
// Pipeline (2 kernels; fill lives WITH compute so it hides under VALU — R11
// showed splitting them exposes the fill as a serial 12 us phase):
//   pass1  : 2048 batch-aligned chunks (512/batch, last = 3072 items).
//            Fire -1 fill stores for own slice; stage batch's 2048 points
//            into LDS SoA (conflict-free stride-1 reads); hot loop tests 16
//            pairs/thread from LDS; epilogue ballots -> 64-slot wave scan ->
//            counts[chunk] + stash (kCap=128).
//   scatter: 256 blocks x 8 chunks. One block-wide scan of all 2048 counts
//            (uint4 + Hillis-Steele), offsets+counts to LDS, then copy each
//            chunk's stash to final positions (recompute fallback if
//            cnt > kCap; block-uniform branch, exact).

namespace {
constexpr int kB = 4;
constexpr int kN = 2048;
constexpr int kP = kN * (kN - 1) / 2;              // 2096128
constexpr long long kTotal = (long long)kB * kP;   // 8384512
constexpr int kBlock = 256;
constexpr int kItems = 16;
constexpr int kChunk = kBlock * kItems;            // 4096
constexpr int kCPB = 512;                          // chunks per batch (last holds 3072)
constexpr int kNChunk = kB * kCPB;                 // 2048
constexpr float kCut2 = 25.0f;                     // 5.0^2
constexpr int kCap = 128;                          // stash slots per chunk
constexpr int kSBlocks = 256;                      // scatter blocks
constexpr int kCPS = kNChunk / kSBlocks;           // 8 chunks per scatter block
}  // namespace

// p in [0,P) -> (i,j), i<j, triu row-major. Closed-form sqrt guess + exact
// integer fixup. C(i) = i*(4095-i)/2. disc < 2^24 so float sqrt is tight.
__device__ __forceinline__ void decode_pair(int p, int& i, int& j) {
  float t = sqrtf((float)(16769025 - 8 * p));
  int ii = (int)((4095.0f - t) * 0.5f);
  ii = ii < 0 ? 0 : (ii > kN - 2 ? kN - 2 : ii);
  while (ii > 0 && (ii * (4095 - ii)) / 2 > p) --ii;
  while (ii < kN - 2 && ((ii + 1) * (4094 - ii)) / 2 <= p) ++ii;
  i = ii;
  j = ii + 1 + (p - (ii * (4095 - ii)) / 2);
}

__global__ __launch_bounds__(kBlock) void pass1_kernel(const float* __restrict__ x,
                                                       uint32_t* __restrict__ counts,
                                                       int2* __restrict__ stash,
                                                       int* __restrict__ out) {
  const int t = threadIdx.x;
  const int wave = t >> 6, lane = t & 63;
  const int bid = blockIdx.x;
  const int b = bid >> 9;            // / kCPB
  const int cw = bid & (kCPB - 1);
  const int pbase = cw * kChunk;
  const int valid = min(kChunk, kP - pbase);        // 4096, or 3072 for cw=511
  const long long fbase = (long long)b * kP + pbase;

  // 1) Fire the -1 fill stores first (independent; hide under compute).
  {
    const int4 m1 = make_int4(-1, -1, -1, -1);
    int4* o0 = (int4*)out + (fbase >> 2);
    int4* o1 = (int4*)(out + kTotal) + (fbase >> 2);
    const int nq = valid >> 10;  // int4s per thread: 4 (full) or 3 (last)
    for (int q = 0; q < nq; ++q) {
      o0[t + q * kBlock] = m1;
      o1[t + q * kBlock] = m1;
    }
  }

  // 2) Stage this batch's 2048 points into LDS, SoA (stride-1 = conflict-free).
  __shared__ float sp[3 * kN];  // [0..2047]=x, [2048..4095]=y, [4096..6143]=z
  {
    const float4* xb4 = (const float4*)(x + (size_t)b * kN * 3);  // 1536 float4
    for (int k = 0; k < 6; ++k) {
      int f4 = t + k * kBlock;
      float4 v = xb4[f4];
      int f = f4 * 4;
      int q = f / 3, r = f - 3 * q;
      float vv[4] = {v.x, v.y, v.z, v.w};
#pragma unroll
      for (int e = 0; e < 4; ++e) {
        sp[r * kN + q] = vv[e];
        if (++r == 3) { r = 0; ++q; }
      }
    }
  }
  __syncthreads();

  // 3) Hot loop: item-major (+256/item), all gathers from LDS.
  int p = pbase + t;
  bool alive = (p < kP);
  int i = 0, j = 1;
  if (alive) decode_pair(p, i, j);
  float pix = sp[i], piy = sp[kN + i], piz = sp[2 * kN + i];

  uint32_t hits = 0;  // bit k = item k is an edge
#pragma unroll
  for (int k = 0; k < kItems; ++k) {
    float dx = pix - sp[j], dy = piy - sp[kN + j], dz = piz - sp[2 * kN + j];
    bool f = alive && (dx * dx + dy * dy + dz * dz <= kCut2);
    if (f) hits |= (1u << k);
    if (k < kItems - 1) {
      j += kBlock;
      if (j >= kN) {
        do {
          int ex = j - kN;
          ++i;
          if (i >= kN - 1) { alive = false; i = 0; j = 1; break; }
          j = i + 1 + ex;
        } while (j >= kN);
        pix = sp[i]; piy = sp[kN + i]; piz = sp[2 * kN + i];
      }
    }
  }

  __shared__ uint32_t slot[kItems * 4];  // 64 (item,wave) counts
  if (t < 64) slot[t] = 0;
  __syncthreads();

  const bool waveany = (__ballot(hits != 0) != 0ULL);  // wave-uniform
  if (waveany) {
#pragma unroll
    for (int k = 0; k < kItems; ++k) {
      unsigned long long m = __ballot((hits >> k) & 1u);
      if (m != 0ULL && lane == 0) slot[k * 4 + wave] = (uint32_t)__popcll(m);
    }
  }
  __syncthreads();
  if (t < 64) {  // one-wave exclusive scan of 64 slots; write chunk total
    uint32_t v = slot[t];
    uint32_t run = v;
    for (int off = 1; off < 64; off <<= 1) {
      uint32_t u = __shfl_up(run, off, 64);
      if (t >= off) run += u;
    }
    slot[t] = run - v;
    if (t == 63) counts[bid] = run;
  }
  __syncthreads();
  if (waveany) {
#pragma unroll
    for (int k = 0; k < kItems; ++k) {
      bool f = (hits >> k) & 1u;
      unsigned long long m = __ballot(f);
      if (m != 0ULL && f) {  // rare: ~6 hits per chunk total
        int hp = pbase + k * kBlock + t;  // < kP (guaranteed by alive)
        int hi, hj;
        decode_pair(hp, hi, hj);
        uint32_t pos = slot[k * 4 + wave] +
                       (uint32_t)__popcll(m & ((1ULL << lane) - 1ULL));
        if (pos < (uint32_t)kCap)
          stash[(size_t)bid * kCap + pos] = make_int2(b * kN + hi, b * kN + hj);
      }
    }
  }
}

__global__ __launch_bounds__(kBlock) void scatter_kernel(const float* __restrict__ x,
                                                         const uint32_t* __restrict__ counts,
                                                         const int2* __restrict__ stash,
                                                         int* __restrict__ out) {
  const int t = threadIdx.x;
  const int bid = blockIdx.x;
  __shared__ uint32_t soff[kNChunk];  // 8 KB: all chunk offsets
  __shared__ uint32_t scnt[kNChunk];  // 8 KB: all chunk counts
  __shared__ uint32_t ssum[kBlock];
  __shared__ uint32_t slot[64];

  // Block-wide scan of all 2048 counts.
  const uint4* c4 = (const uint4*)counts;
  uint4 v0 = c4[t * 2], v1 = c4[t * 2 + 1];
  uint32_t c[8] = {v0.x, v0.y, v0.z, v0.w, v1.x, v1.y, v1.z, v1.w};
  uint32_t loc[8], sum = 0;
#pragma unroll
  for (int q = 0; q < 8; ++q) { loc[q] = sum; sum += c[q]; }
  ssum[t] = sum;
  __syncthreads();
  for (int o = 1; o < kBlock; o <<= 1) {  // Hillis-Steele inclusive
    uint32_t u = (t >= o) ? ssum[t - o] : 0u;
    __syncthreads();
    if (t >= o) ssum[t] += u;
    __syncthreads();
  }
  const uint32_t tbase = (t == 0) ? 0u : ssum[t - 1];
#pragma unroll
  for (int q = 0; q < 8; ++q) {
    soff[t * 8 + q] = tbase + loc[q];
    scnt[t * 8 + q] = c[q];
  }
  __syncthreads();

  // Copy this block's 8 chunks to final positions.
  for (int q = 0; q < kCPS; ++q) {
    const int cc = bid * kCPS + q;
    const uint32_t cnt = scnt[cc];   // LDS broadcast (block-uniform)
    if (cnt == 0) continue;
    const uint32_t off = soff[cc];
    if (cnt <= (uint32_t)kCap) {
      if (t < (int)cnt) {  // cnt <= 128 < 256: single step
        int2 v = stash[(size_t)cc * kCap + t];
        out[off + t] = v.x;
        out[(size_t)kTotal + off + t] = v.y;
      }
      continue;
    }
    // Overflow fallback (cnt > kCap, block-uniform): recompute this chunk's
    // edges with ballot ranks, write over the -1s. Deterministic + exact.
    const int wave = t >> 6, lane = t & 63;
    const int b = cc >> 9;
    const int pbase = (cc & (kCPB - 1)) * kChunk;
    const float* xb = x + (size_t)b * kN * 3;
    if (t < 64) slot[t] = 0;
    __syncthreads();
    uint32_t hits = 0;
#pragma unroll
    for (int k = 0; k < kItems; ++k) {
      int p = pbase + k * kBlock + t;
      bool f = false;
      if (p < kP) {
        int hi, hj;
        decode_pair(p, hi, hj);
        float dx = xb[3 * hi] - xb[3 * hj];
        float dy = xb[3 * hi + 1] - xb[3 * hj + 1];
        float dz = xb[3 * hi + 2] - xb[3 * hj + 2];
        f = dx * dx + dy * dy + dz * dz <= kCut2;
      }
      if (f) hits |= (1u << k);
      unsigned long long m = __ballot(f);
      if (m != 0ULL && lane == 0) slot[k * 4 + wave] = (uint32_t)__popcll(m);
    }
    __syncthreads();
    if (t < 64) {
      uint32_t v = slot[t];
      uint32_t run = v;
      for (int o = 1; o < 64; o <<= 1) {
        uint32_t u = __shfl_up(run, o, 64);
        if (t >= o) run += u;
      }
      slot[t] = run - v;
    }
    __syncthreads();
#pragma unroll
    for (int k = 0; k < kItems; ++k) {
      bool f = (hits >> k) & 1u;
      unsigned long long m = __ballot(f);
      if (m != 0ULL && f) {
        int p = pbase + k * kBlock + t;
        int hi, hj;
        decode_pair(p, hi, hj);
        uint32_t pos = off + slot[k * 4 + wave] +
                       (uint32_t)__popcll(m & ((1ULL << lane) - 1ULL));
        out[pos] = b * kN + hi;
        out[(size_t)kTotal + pos] = b * kN + hj;
      }
    }
    __syncthreads();  // slot reused next chunk
  }
}

extern "C" void kernel_launch(void* const* d_in, const int* in_sizes, int n_in,
                              void* d_out, int out_size, void* d_ws, size_t ws_size,
                              hipStream_t stream) {
  const float* x = (const float*)d_in[0];
  int* out = (int*)d_out;
  uint32_t* counts = (uint32_t*)d_ws;                 // [2048]
  int2* stash = (int2*)(counts + kNChunk);            // [2048 * kCap] ~2.1 MB

  hipLaunchKernelGGL(pass1_kernel, dim3(kNChunk), dim3(kBlock), 0, stream, x, counts,
                     stash, out);
  hipLaunchKernelGGL(scatter_kernel, dim3(kSBlocks), dim3(kBlock), 0, stream, x,
                     counts, stash, out);
}